// Round 3
// baseline (18280.466 us; speedup 1.0000x reference)
//
#include <hip/hip_runtime.h>

typedef __bf16 bf16;
typedef __bf16 bf8v __attribute__((ext_vector_type(8)));
typedef float  f4v  __attribute__((ext_vector_type(4)));

#define L_   1024
#define D_   1024
#define H_   16
#define HD_  64
#define FF_  4096
#define NL_  8
#define NTOK 2048

// Dual-pointer dtype-branching load: f==1 -> float32 at pf; f==0 -> bf16 at pb.
// (pb/pf are the SAME tensor base advanced by the layer offset at the dtype's stride;
//  host doesn't know the dtype, so both candidates are precomputed.)
__device__ __forceinline__ float ldf2(const void* pb, const void* pf, size_t i, int f) {
  return f ? ((const float*)pf)[i] : (float)((const bf16*)pb)[i];
}

// ---------------- dtype detector ----------------
// bet_amounts is uniform[0,1). As bf16[2048]: no uint16 has the sign bit set.
// As float32[2048]: even uint16s are random low-mantissa bits -> ~25% sign bits.
// Reads only 2048 bytes: safe under either dtype.
__global__ void dtype_detect(const unsigned short* __restrict__ raw, int* __restrict__ flag)
{
  int c = 0;
  for (int i = threadIdx.x; i < 1024; i += 64) c += (raw[i] >> 15) & 1;
#pragma unroll
  for (int off = 32; off > 0; off >>= 1) c += __shfl_down(c, off);
  if (threadIdx.x == 0) *flag = (c > 16) ? 1 : 0;
}

// ---------------- ws-too-small marker: absmax ~= 100 signals workspace overflow ----------------
__global__ void ws_marker(const int* __restrict__ flag, void* __restrict__ out)
{
  const int i = blockIdx.x * 256 + threadIdx.x;   // 0..2047
  if (*flag) ((float*)out)[i] = 100.0f;
  else       ((bf16*)out)[i]  = (bf16)100.0f;
}

// ---------------- embed: tok=[card|action|bet*W+b] -> x = tok@in_W + in_b + posenc ----------------
__global__ __launch_bounds__(256) void embed_kernel(
    const int* __restrict__ card_ids, const int* __restrict__ action_ids,
    const void* __restrict__ bet, const void* __restrict__ card_tab,
    const void* __restrict__ action_tab, const void* __restrict__ bet_W,
    const void* __restrict__ bet_b, const void* __restrict__ in_W,
    const void* __restrict__ in_b, const int* __restrict__ dflag,
    bf16* __restrict__ x)
{
  const int f = *dflag;
  const int t = blockIdx.x;          // 0..2047
  const int l = t & (L_ - 1);
  const int tid = threadIdx.x;
  __shared__ float tok[48];
  if (tid < 48) {
    float v;
    if (tid < 16)      v = ldf2(card_tab, card_tab, card_ids[t] * 16 + tid, f);
    else if (tid < 32) v = ldf2(action_tab, action_tab, action_ids[t] * 16 + (tid - 16), f);
    else               v = ldf2(bet, bet, t, f) * ldf2(bet_W, bet_W, tid - 32, f)
                           + ldf2(bet_b, bet_b, tid - 32, f);
    tok[tid] = v;
  }
  __syncthreads();
#pragma unroll
  for (int r = 0; r < 4; ++r) {
    const int n = tid + 256 * r;
    float acc = ldf2(in_b, in_b, n, f);
    for (int c = 0; c < 48; ++c) acc += tok[c] * ldf2(in_W, in_W, c * D_ + n, f);
    const float ang = (float)l * expf((float)(n & ~1) * (-9.210340371976184f / (float)D_));
    acc += (n & 1) ? cosf(ang) : sinf(ang);
    x[(size_t)t * D_ + n] = (bf16)acc;
  }
}

// ---------------- MFMA GEMM: C[M,N] = A[M,K]@W[K,N] + bias, optional ReLU ----------------
// A: bf16 intermediate (16B vector loads). W/bias: raw input, dtype via flag.
// 128x128 tile, BK=32, 4 waves 2x2, each wave 4x4 mfma_f32_16x16x32_bf16.
// LDS stride 40 elems (5x16B groups) for conflict spread.
template<int RELU>
__global__ __launch_bounds__(256) void gemm_kernel(
    const bf16* __restrict__ A, const void* __restrict__ Wb, const void* __restrict__ Wf,
    const void* __restrict__ Bb, const void* __restrict__ Bf,
    const int* __restrict__ dflag, bf16* __restrict__ C, int M, int N, int K)
{
  const int f = *dflag;
  const int LDS_ = 40;
  __shared__ bf16 As[128 * 40];
  __shared__ bf16 Bs[128 * 40];
  const int tid  = threadIdx.x;
  const int n0   = blockIdx.x * 128;
  const int m0   = blockIdx.y * 128;
  const int lane = tid & 63;
  const int wave = tid >> 6;
  const int wm   = (wave >> 1) * 64;
  const int wn   = (wave & 1) * 64;
  const int fr   = lane & 15;   // fragment outer index (m or n)
  const int quad = lane >> 4;   // k-quad

  f4v acc[4][4];
#pragma unroll
  for (int i = 0; i < 4; ++i)
#pragma unroll
    for (int j = 0; j < 4; ++j) { f4v z = {0.f, 0.f, 0.f, 0.f}; acc[i][j] = z; }

  const int ar = tid >> 1;            // A row 0..127
  const int ak = (tid & 1) * 16;      // A k-half
  const int bn = tid & 127;           // B col 0..127
  const int bk = (tid >> 7) * 16;     // B k-half

  const bf16* Aptr = A + (size_t)(m0 + ar) * K + ak;

  for (int k0 = 0; k0 < K; k0 += 32) {
    bf8v a0 = *(const bf8v*)(Aptr + k0);
    bf8v a1 = *(const bf8v*)(Aptr + k0 + 8);
    const size_t wbase = (size_t)(k0 + bk) * N + n0 + bn;
    bf8v blo, bhi;
#pragma unroll
    for (int j = 0; j < 8; ++j) {
      blo[j] = (bf16)ldf2(Wb, Wf, wbase + (size_t)j * N, f);
      bhi[j] = (bf16)ldf2(Wb, Wf, wbase + (size_t)(j + 8) * N, f);
    }
    *(bf8v*)(&As[ar * LDS_ + ak])     = a0;
    *(bf8v*)(&As[ar * LDS_ + ak + 8]) = a1;
    *(bf8v*)(&Bs[bn * LDS_ + bk])     = blo;
    *(bf8v*)(&Bs[bn * LDS_ + bk + 8]) = bhi;
    __syncthreads();

    bf8v af[4], bfv[4];
#pragma unroll
    for (int mt = 0; mt < 4; ++mt)
      af[mt] = *(const bf8v*)(&As[(wm + mt * 16 + fr) * LDS_ + quad * 8]);
#pragma unroll
    for (int nt = 0; nt < 4; ++nt)
      bfv[nt] = *(const bf8v*)(&Bs[(wn + nt * 16 + fr) * LDS_ + quad * 8]);
#pragma unroll
    for (int mt = 0; mt < 4; ++mt)
#pragma unroll
      for (int nt = 0; nt < 4; ++nt)
        acc[mt][nt] = __builtin_amdgcn_mfma_f32_16x16x32_bf16(af[mt], bfv[nt], acc[mt][nt], 0, 0, 0);
    __syncthreads();
  }

  // C/D layout: col=lane&15 (N, from B-frag), row=quad*4+reg (M, from A-frag)
#pragma unroll
  for (int nt = 0; nt < 4; ++nt) {
    const int col = n0 + wn + nt * 16 + fr;
    const float bv = ldf2(Bb, Bf, col, f);
#pragma unroll
    for (int mt = 0; mt < 4; ++mt) {
#pragma unroll
      for (int r = 0; r < 4; ++r) {
        const int row = m0 + wm + mt * 16 + quad * 4 + r;
        float v = acc[mt][nt][r] + bv;
        if (RELU) v = fmaxf(v, 0.0f);
        C[(size_t)row * N + col] = (bf16)v;
      }
    }
  }
}

// ---------------- causal attention, one block per (b,h,q) ----------------
// qkv row layout: [s*1024 + h*64 + d], s=0:q 1:k 2:v
__global__ __launch_bounds__(256) void attn_kernel(
    const bf16* __restrict__ qkv, bf16* __restrict__ attno)
{
  const int q  = blockIdx.x;
  const int bh = blockIdx.y;
  const int b  = bh >> 4;
  const int h  = bh & 15;
  const int tid = threadIdx.x;

  __shared__ float sq[HD_];
  __shared__ float sc[L_];
  __shared__ float red[4];
  __shared__ float part[4][HD_];

  const size_t rs = 3 * D_;
  const bf16* qrow = qkv + (size_t)(b * L_ + q) * rs + h * HD_;
  if (tid < HD_) sq[tid] = (float)qrow[tid] * 0.125f;   // 1/sqrt(64)
  __syncthreads();

  const int nk = q + 1;
  const bf16* kbase = qkv + (size_t)(b * L_) * rs + D_ + h * HD_;
  for (int j = tid; j < nk; j += 256) {
    const bf8v* kp = (const bf8v*)(kbase + (size_t)j * rs);
    float dot = 0.f;
#pragma unroll
    for (int c = 0; c < 8; ++c) {
      bf8v kv = kp[c];
#pragma unroll
      for (int e = 0; e < 8; ++e) dot += sq[c * 8 + e] * (float)kv[e];
    }
    sc[j] = dot;
  }
  __syncthreads();

  float mx = -1e30f;
  for (int j = tid; j < nk; j += 256) mx = fmaxf(mx, sc[j]);
#pragma unroll
  for (int off = 32; off > 0; off >>= 1) mx = fmaxf(mx, __shfl_down(mx, off));
  if ((tid & 63) == 0) red[tid >> 6] = mx;
  __syncthreads();
  mx = fmaxf(fmaxf(red[0], red[1]), fmaxf(red[2], red[3]));
  __syncthreads();

  float s = 0.f;
  for (int j = tid; j < nk; j += 256) {
    float p = __expf(sc[j] - mx);
    sc[j] = p;
    s += p;
  }
#pragma unroll
  for (int off = 32; off > 0; off >>= 1) s += __shfl_down(s, off);
  if ((tid & 63) == 0) red[tid >> 6] = s;
  __syncthreads();
  const float inv = 1.f / (red[0] + red[1] + red[2] + red[3]);

  const int d = tid & 63;
  const int g = tid >> 6;
  const bf16* vp = qkv + (size_t)(b * L_) * rs + 2 * D_ + h * HD_ + d;
  float o = 0.f;
  for (int j = g; j < nk; j += 4) o += sc[j] * (float)vp[(size_t)j * rs];
  part[g][d] = o;
  __syncthreads();
  if (tid < HD_) {
    float r = (part[0][d] + part[1][d] + part[2][d] + part[3][d]) * inv;
    attno[(size_t)(b * L_ + q) * D_ + h * HD_ + d] = (bf16)r;
  }
}

// ---------------- fused residual-add + LayerNorm ----------------
__global__ __launch_bounds__(256) void add_ln_kernel(
    const bf16* __restrict__ xin, const bf16* __restrict__ yin,
    const void* __restrict__ gb, const void* __restrict__ gf,
    const void* __restrict__ bbb, const void* __restrict__ bbf,
    const int* __restrict__ dflag, bf16* __restrict__ xout)
{
  const int f = *dflag;
  const int t = blockIdx.x;
  const int tid = threadIdx.x;
  __shared__ float z[D_];
  __shared__ float red[4];
  const size_t base = (size_t)t * D_;
  float ls = 0.f;
#pragma unroll
  for (int r = 0; r < 4; ++r) {
    const int dd = tid + 256 * r;
    float v = (float)xin[base + dd] + (float)yin[base + dd];
    z[dd] = v;
    ls += v;
  }
#pragma unroll
  for (int off = 32; off > 0; off >>= 1) ls += __shfl_down(ls, off);
  if ((tid & 63) == 0) red[tid >> 6] = ls;
  __syncthreads();
  const float mu = (red[0] + red[1] + red[2] + red[3]) * (1.0f / D_);
  __syncthreads();
  float lv = 0.f;
#pragma unroll
  for (int r = 0; r < 4; ++r) {
    const float dv = z[tid + 256 * r] - mu;
    lv += dv * dv;
  }
#pragma unroll
  for (int off = 32; off > 0; off >>= 1) lv += __shfl_down(lv, off);
  if ((tid & 63) == 0) red[tid >> 6] = lv;
  __syncthreads();
  const float rstd = rsqrtf((red[0] + red[1] + red[2] + red[3]) * (1.0f / D_) + 1e-5f);
#pragma unroll
  for (int r = 0; r < 4; ++r) {
    const int dd = tid + 256 * r;
    const float v = (z[dd] - mu) * rstd * ldf2(gb, gf, dd, f) + ldf2(bbb, bbf, dd, f);
    xout[base + dd] = (bf16)v;
  }
}

// ---------------- final gather: out = x[:, -1], dtype-branching store ----------------
__global__ void out_copy(const bf16* __restrict__ x, const int* __restrict__ dflag,
                         void* __restrict__ out)
{
  const int f = *dflag;
  const int i = blockIdx.x * 256 + threadIdx.x;   // 0..2047
  const int b = i >> 10;
  const int dd = i & 1023;
  const float v = (float)x[(size_t)(b * L_ + (L_ - 1)) * D_ + dd];
  if (f) ((float*)out)[i] = v;
  else   ((bf16*)out)[i]  = (bf16)v;
}

// host helper: advance a raw input pointer by an element offset under both dtype hypotheses
static inline const void* adv2(const void* p, size_t eoff) { return (const char*)p + eoff * 2; }
static inline const void* adv4(const void* p, size_t eoff) { return (const char*)p + eoff * 4; }

extern "C" void kernel_launch(void* const* d_in, const int* in_sizes, int n_in,
                              void* d_out, int out_size, void* d_ws, size_t ws_size,
                              hipStream_t stream)
{
  const int* card_ids   = (const int*)d_in[0];
  const int* action_ids = (const int*)d_in[1];

  char* ws = (char*)d_ws;
  int* dflag = (int*)ws;
  // buffers at +4KB; lifetimes let attno+qkv share the 16MB hidden region:
  //   qkv    [4K, 4K+12M)       live gemm1->attn
  //   attno  [4K+12M, 4K+16M)   live attn->out-proj
  //   hidden [4K, 4K+16M)       live ffn1->ffn2 (qkv+attno dead)
  //   proj   [4K+16M, +20M) | x [+20M,+24M) | x2 [+24M,+28M)
  const size_t MB = 1u << 20;
  bf16* qkvbuf = (bf16*)(ws + 4096);
  bf16* attno  = (bf16*)(ws + 4096 + 12 * MB);
  bf16* hffn   = (bf16*)(ws + 4096);
  bf16* proj   = (bf16*)(ws + 4096 + 16 * MB);
  bf16* xbuf   = (bf16*)(ws + 4096 + 20 * MB);
  bf16* x2buf  = (bf16*)(ws + 4096 + 24 * MB);

  dtype_detect<<<1, 64, 0, stream>>>((const unsigned short*)d_in[2], dflag);

  if (ws_size < 4096 + 28 * MB) {            // constant across calls -> capture-safe
    ws_marker<<<NTOK / 256, 256, 0, stream>>>(dflag, d_out);
    return;
  }

  embed_kernel<<<NTOK, 256, 0, stream>>>(card_ids, action_ids, d_in[2], d_in[3],
                                         d_in[4], d_in[5], d_in[6], d_in[7], d_in[8],
                                         dflag, xbuf);

  for (int i = 0; i < NL_; ++i) {
    const size_t qW = (size_t)i * D_ * 3 * D_, qB = (size_t)i * 3 * D_;
    const size_t oW = (size_t)i * D_ * D_,     oB = (size_t)i * D_;
    const size_t w1 = (size_t)i * D_ * FF_,    b1 = (size_t)i * FF_;
    const size_t w2 = (size_t)i * FF_ * D_,    b2 = (size_t)i * D_;
    const size_t ln = (size_t)i * D_;

    gemm_kernel<0><<<dim3(3 * D_ / 128, NTOK / 128), 256, 0, stream>>>(
        xbuf, adv2(d_in[9], qW), adv4(d_in[9], qW), adv2(d_in[10], qB), adv4(d_in[10], qB),
        dflag, qkvbuf, NTOK, 3 * D_, D_);
    attn_kernel<<<dim3(L_, 2 * H_), 256, 0, stream>>>(qkvbuf, attno);
    gemm_kernel<0><<<dim3(D_ / 128, NTOK / 128), 256, 0, stream>>>(
        attno, adv2(d_in[11], oW), adv4(d_in[11], oW), adv2(d_in[12], oB), adv4(d_in[12], oB),
        dflag, proj, NTOK, D_, D_);
    add_ln_kernel<<<NTOK, 256, 0, stream>>>(
        xbuf, proj, adv2(d_in[13], ln), adv4(d_in[13], ln), adv2(d_in[14], ln), adv4(d_in[14], ln),
        dflag, x2buf);
    gemm_kernel<1><<<dim3(FF_ / 128, NTOK / 128), 256, 0, stream>>>(
        x2buf, adv2(d_in[15], w1), adv4(d_in[15], w1), adv2(d_in[16], b1), adv4(d_in[16], b1),
        dflag, hffn, NTOK, FF_, D_);
    gemm_kernel<0><<<dim3(D_ / 128, NTOK / 128), 256, 0, stream>>>(
        hffn, adv2(d_in[17], w2), adv4(d_in[17], w2), adv2(d_in[18], b2), adv4(d_in[18], b2),
        dflag, proj, NTOK, D_, FF_);
    add_ln_kernel<<<NTOK, 256, 0, stream>>>(
        x2buf, proj, adv2(d_in[19], ln), adv4(d_in[19], ln), adv2(d_in[20], ln), adv4(d_in[20], ln),
        dflag, xbuf);
  }

  out_copy<<<NTOK / 256, 256, 0, stream>>>(xbuf, dflag, d_out);
}